// Round 1
// baseline (201.597 us; speedup 1.0000x reference)
//
#include <hip/hip_runtime.h>

#define D 16

// Edge-parallel message + scatter-add. 16 lanes per edge: lane o computes
// msg[e][o] = sum_i W[widx[e]][o][i] * x[u[e]][i], then atomicAdd into
// out[v[e]*16 + o]. W row load is 64B/lane coalesced; x row load is
// 64B per 16-lane group coalesced; x values broadcast via __shfl width=16.
__global__ __launch_bounds__(256) void edge_scatter_kernel(
    const float* __restrict__ x,
    const float* __restrict__ W,
    const int* __restrict__ u,
    const int* __restrict__ v,
    const int* __restrict__ widx,
    float* __restrict__ out,
    int E) {
    int tid = blockIdx.x * 256 + threadIdx.x;
    int e = tid >> 4;
    int o = tid & 15;
    if (e >= E) return;

    int w  = widx[e];
    int uu = u[e];
    int vv = v[e];

    const float* Wr = W + (size_t)w * (D * D) + (size_t)o * D;
    float4 w0 = *(const float4*)(Wr + 0);
    float4 w1 = *(const float4*)(Wr + 4);
    float4 w2 = *(const float4*)(Wr + 8);
    float4 w3 = *(const float4*)(Wr + 12);

    float xv = x[(size_t)uu * D + o];

    float acc = 0.0f;
    acc += w0.x * __shfl(xv,  0, 16);
    acc += w0.y * __shfl(xv,  1, 16);
    acc += w0.z * __shfl(xv,  2, 16);
    acc += w0.w * __shfl(xv,  3, 16);
    acc += w1.x * __shfl(xv,  4, 16);
    acc += w1.y * __shfl(xv,  5, 16);
    acc += w1.z * __shfl(xv,  6, 16);
    acc += w1.w * __shfl(xv,  7, 16);
    acc += w2.x * __shfl(xv,  8, 16);
    acc += w2.y * __shfl(xv,  9, 16);
    acc += w2.z * __shfl(xv, 10, 16);
    acc += w2.w * __shfl(xv, 11, 16);
    acc += w3.x * __shfl(xv, 12, 16);
    acc += w3.y * __shfl(xv, 13, 16);
    acc += w3.z * __shfl(xv, 14, 16);
    acc += w3.w * __shfl(xv, 15, 16);

    atomicAdd(out + (size_t)vv * D + o, acc);
}

// In-place ReLU over the output buffer (vectorized float4).
__global__ __launch_bounds__(256) void relu_kernel(float* __restrict__ out, int n4) {
    int i = blockIdx.x * 256 + threadIdx.x;
    if (i >= n4) return;
    float4* p = (float4*)out + i;
    float4 val = *p;
    val.x = fmaxf(val.x, 0.0f);
    val.y = fmaxf(val.y, 0.0f);
    val.z = fmaxf(val.z, 0.0f);
    val.w = fmaxf(val.w, 0.0f);
    *p = val;
}

extern "C" void kernel_launch(void* const* d_in, const int* in_sizes, int n_in,
                              void* d_out, int out_size, void* d_ws, size_t ws_size,
                              hipStream_t stream) {
    const float* x    = (const float*)d_in[0];
    const float* W    = (const float*)d_in[1];
    const int*   u    = (const int*)d_in[2];
    const int*   v    = (const int*)d_in[3];
    const int*   widx = (const int*)d_in[4];
    float* out = (float*)d_out;

    int E = in_sizes[2];  // number of edges

    // d_out is poisoned with 0xAA before every timed launch; zero it for the
    // atomic accumulation.
    hipMemsetAsync(d_out, 0, (size_t)out_size * sizeof(float), stream);

    int total_threads = E * 16;
    int blocks = (total_threads + 255) / 256;
    edge_scatter_kernel<<<blocks, 256, 0, stream>>>(x, W, u, v, widx, out, E);

    int n4 = out_size / 4;
    int rblocks = (n4 + 255) / 256;
    relu_kernel<<<rblocks, 256, 0, stream>>>(out, n4);
}